// Round 2
// baseline (3564.644 us; speedup 1.0000x reference)
//
#include <hip/hip_runtime.h>

// Problem constants (fixed by reference)
#define K3c    27
#define Mc     100000
#define NINc   200000
#define NOUTc  400000
#define Cc     128
#define EPSc   1e-5f

#define NBUCK  6250          // global 64-row output buckets (NOUTc/64)
#define NCNT   (NBUCK * K3c) // 168,750 keys: key = bucket*27 + k
#define BPK    391           // map-pass blocks per k (391*256 >= 100000)
#define SCANB  165           // scan blocks of 1024 (165*1024 >= NCNT)

// ws layout (byte offsets)
#define WS_STATS   0u          // 512 floats: sum | ssq | scale | shift
#define WS_COUNTS  4096u       // NCNT u32
#define WS_AUX     700416u     // SCANB u32 scan partials
#define WS_SPK     1048576u    // 2.7M u32 packed sorted pairs (im|k|omlow)
#define WS_WFH     25165824u   // 27*2048 lanes * 8 shorts  (884,736 B)
#define WS_WFL     26214400u   // same

typedef __attribute__((ext_vector_type(8))) short short8;
typedef __attribute__((ext_vector_type(4))) float f32x4;

__device__ inline unsigned fbits(float f) { return __builtin_bit_cast(unsigned, f); }
__device__ inline float bfloat(unsigned u) { return __builtin_bit_cast(float, u); }

// pack truncated-bf16 of (f0,f1) into one u32 (f0 -> low16, f1 -> high16)
__device__ inline unsigned pack_hi2(float f0, float f1) {
    return (fbits(f0) >> 16) | (fbits(f1) & 0xFFFF0000u);
}
__device__ inline float trunc_bf16_f(float f) { return bfloat(fbits(f) & 0xFFFF0000u); }

__device__ inline unsigned short bf16_rne(float f) {
    unsigned u = fbits(f);
    u += 0x7FFFu + ((u >> 16) & 1u);
    return (unsigned short)(u >> 16);
}

// ---------------------------------------------------------------------------
// Kernel 1: zero counters + stats (output needs no zeroing: tiles fully written)
// ---------------------------------------------------------------------------
__global__ __launch_bounds__(256) void zero2_kernel(float* __restrict__ stats,
                                                    unsigned* __restrict__ counts) {
    int idx = blockIdx.x * 256 + threadIdx.x;
    if (idx < NCNT) counts[idx] = 0u;
    if (idx < 512) stats[idx] = 0.f;
}

// ---------------------------------------------------------------------------
// Kernel 2: W -> per-lane MFMA B-fragment layout, RNE hi/lo bf16 split
// ---------------------------------------------------------------------------
__global__ __launch_bounds__(256) void wprep_kernel(const float* __restrict__ W,
                                                    short8* __restrict__ wfh,
                                                    short8* __restrict__ wfl) {
    int tid = blockIdx.x * 256 + threadIdx.x;     // grid = 216 blocks exactly
    int k     = tid >> 11;
    int rem   = tid & 2047;
    int kstep = rem >> 9;
    int cb    = (rem >> 6) & 7;
    int lane  = rem & 63;
    int n   = cb * 16 + (lane & 15);
    int kk0 = kstep * 32 + (lane >> 4) * 8;
    const float* src = W + k * (Cc * Cc) + kk0 * Cc + n;
    short8 h, l;
#pragma unroll
    for (int j = 0; j < 8; ++j) {
        float f = src[j * Cc];
        unsigned short hb = bf16_rne(f);
        h[j] = (short)hb;
        float hf = bfloat(((unsigned)hb) << 16);
        l[j] = (short)bf16_rne(f - hf);
    }
    wfh[tid] = h;
    wfl[tid] = l;
}

// ---------------------------------------------------------------------------
// Kernel 3: histogram of pairs by global key (bucket-major, k-minor)
// ---------------------------------------------------------------------------
__global__ __launch_bounds__(256) void hist2_kernel(const int* __restrict__ out_maps,
                                                    unsigned* __restrict__ counts) {
    int b = blockIdx.x;
    int k = b / BPK;
    int m = (b - k * BPK) * 256 + threadIdx.x;
    if (m < Mc) {
        int om = out_maps[k * Mc + m];
        atomicAdd(&counts[(unsigned)(om >> 6) * 27u + (unsigned)k], 1u);
    }
}

// ---------------------------------------------------------------------------
// Kernel 4a/4b/4c: multi-block exclusive scan over NCNT counters.
// ---------------------------------------------------------------------------
__global__ __launch_bounds__(1024) void scan_a(unsigned* __restrict__ counts,
                                               unsigned* __restrict__ aux) {
    __shared__ unsigned lds[1024];
    const int t = threadIdx.x;
    const int i = blockIdx.x * 1024 + t;
    unsigned v = (i < NCNT) ? counts[i] : 0u;
    lds[t] = v;
    __syncthreads();
    for (int off = 1; off < 1024; off <<= 1) {
        unsigned x = (t >= off) ? lds[t - off] : 0u;
        __syncthreads();
        lds[t] += x;
        __syncthreads();
    }
    if (i < NCNT) counts[i] = lds[t] - v;          // exclusive within block
    if (t == 1023) aux[blockIdx.x] = lds[1023];    // block total
}

__global__ __launch_bounds__(256) void scan_b(unsigned* __restrict__ aux) {
    __shared__ unsigned lds[256];
    const int t = threadIdx.x;
    unsigned v = (t < SCANB) ? aux[t] : 0u;
    lds[t] = v;
    __syncthreads();
    for (int off = 1; off < 256; off <<= 1) {
        unsigned x = (t >= off) ? lds[t - off] : 0u;
        __syncthreads();
        lds[t] += x;
        __syncthreads();
    }
    if (t < SCANB) aux[t] = lds[t] - v;            // exclusive block offsets
}

__global__ __launch_bounds__(1024) void scan_c(unsigned* __restrict__ counts,
                                               const unsigned* __restrict__ aux) {
    const int i = blockIdx.x * 1024 + threadIdx.x;
    if (i < NCNT) counts[i] += aux[blockIdx.x];
}

// ---------------------------------------------------------------------------
// Kernel 5: scatter packed pairs into globally-sorted order.
// After this, counts[key] = END offset of that key's range.
// Packed pair: im (bits 0-17) | k (18-22) | om&63 (23-28)
// ---------------------------------------------------------------------------
__global__ __launch_bounds__(256) void build2_kernel(const int* __restrict__ in_maps,
                                                     const int* __restrict__ out_maps,
                                                     unsigned* __restrict__ offs,
                                                     unsigned* __restrict__ sorted_pk) {
    int b = blockIdx.x;
    int k = b / BPK;
    int m = (b - k * BPK) * 256 + threadIdx.x;
    if (m < Mc) {
        int om = out_maps[k * Mc + m];
        int im = in_maps[k * Mc + m];
        unsigned pos = atomicAdd(&offs[(unsigned)(om >> 6) * 27u + (unsigned)k], 1u);
        sorted_pk[pos] = (unsigned)im | ((unsigned)k << 18) | ((unsigned)(om & 63) << 23);
    }
}

// ---------------------------------------------------------------------------
// Kernel 6: output-major GEMM, v2.
// Block = one 64-row output tile; static k loop, all 4 waves per group.
// Waves are COLUMN-split: wave w owns cols [w*32, w*32+32); its B fragments
// (16 x short8) are loaded once per k-group and held in registers.
// A rows staged cooperatively (coalesced float4) into LDS split-bf16 [32][136].
// Scatter via ds_add_f32 (atomicAdd on shared) into padded accs[64][132].
// Tile written once; per-channel sum/ssq fused.
// ---------------------------------------------------------------------------
__global__ __launch_bounds__(256) void gemm3_kernel(
    const float* __restrict__ feats,
    const short8* __restrict__ wfh, const short8* __restrict__ wfl,
    const unsigned* __restrict__ counts,      // end offsets per key
    const unsigned* __restrict__ sorted_pk,
    float* __restrict__ out, float* __restrict__ stats)
{
    __shared__ float accs[64 * 132];          // 33,792 B, +4 pad vs 128
    __shared__ short fh[32 * 136];            // 8,704 B
    __shared__ short fl[32 * 136];            // 8,704 B
    __shared__ int   omr[32];
    __shared__ float sred[Cc], qred[Cc];

    const int b = blockIdx.x;
    const int t = threadIdx.x;

    {   // zero accs
        f32x4* a4 = (f32x4*)accs;
        const f32x4 z = {0.f, 0.f, 0.f, 0.f};
        for (int i = t; i < 64 * 33; i += 256) a4[i] = z;
    }
    const unsigned gbase = (b == 0) ? 0u : counts[b * 27 - 1];
    __syncthreads();

    const int lane = t & 63;
    const int wave = t >> 6;
    const int m    = lane & 15;
    const int quad = lane >> 4;
    const int cb0  = wave * 2;

    unsigned sk = gbase;
    for (int kk = 0; kk < K3c; ++kk) {
        const unsigned ek = counts[b * 27 + kk];
        const int cnt = (int)(ek - sk);
        if (cnt > 0) {
            // --- B fragments for this k, this wave's two col-blocks, in regs ---
            short8 bh0[4], bh1[4], bl0[4], bl1[4];
#pragma unroll
            for (int ks = 0; ks < 4; ++ks) {
                const int fb = ((kk * 4 + ks) * 8) * 64 + lane;
                bh0[ks] = wfh[fb + cb0 * 64];
                bh1[ks] = wfh[fb + (cb0 + 1) * 64];
                bl0[ks] = wfl[fb + cb0 * 64];
                bl1[ks] = wfl[fb + (cb0 + 1) * 64];
            }
            for (int c0 = 0; c0 < cnt; c0 += 32) {
                const int nrows = min(32, cnt - c0);
                {   // --- cooperative coalesced A stage + split ---
                    const int r  = t >> 3;                 // 0..31
                    const int c8 = t & 7;                  // 8 threads/row
                    const bool ok = (r < nrows);
                    unsigned pk = ok ? sorted_pk[sk + c0 + r] : 0u;
                    if (c8 == 0) omr[r] = ok ? (int)((pk >> 23) & 63u) : 0;
                    const float* src = feats + (long)(pk & 0x3FFFFu) * Cc + c8 * 4;
                    unsigned* fh32 = (unsigned*)fh;
                    unsigned* fl32 = (unsigned*)fl;
#pragma unroll
                    for (int p = 0; p < 4; ++p) {
                        float4 v = ok ? *(const float4*)(src + p * 32)
                                      : make_float4(0.f, 0.f, 0.f, 0.f);
                        int idx = (r * 136 + p * 32 + c8 * 4) >> 1;
                        fh32[idx]     = pack_hi2(v.x, v.y);
                        fh32[idx + 1] = pack_hi2(v.z, v.w);
                        float lx = v.x - trunc_bf16_f(v.x);
                        float ly = v.y - trunc_bf16_f(v.y);
                        float lz = v.z - trunc_bf16_f(v.z);
                        float lw = v.w - trunc_bf16_f(v.w);
                        fl32[idx]     = pack_hi2(lx, ly);
                        fl32[idx + 1] = pack_hi2(lz, lw);
                    }
                }
                __syncthreads();

                const int S = (nrows + 15) >> 4;
                for (int s = 0; s < S; ++s) {
                    f32x4 acc0 = {0.f, 0.f, 0.f, 0.f};
                    f32x4 acc1 = {0.f, 0.f, 0.f, 0.f};
                    const short* ah = fh + (s * 16 + m) * 136 + quad * 8;
                    const short* al = fl + (s * 16 + m) * 136 + quad * 8;
#pragma unroll
                    for (int ks = 0; ks < 4; ++ks) {
                        short8 a_hi = *(const short8*)(ah + ks * 32);
                        short8 a_lo = *(const short8*)(al + ks * 32);
                        acc0 = __builtin_amdgcn_mfma_f32_16x16x32_bf16(a_hi, bh0[ks], acc0, 0, 0, 0);
                        acc0 = __builtin_amdgcn_mfma_f32_16x16x32_bf16(a_lo, bh0[ks], acc0, 0, 0, 0);
                        acc0 = __builtin_amdgcn_mfma_f32_16x16x32_bf16(a_hi, bl0[ks], acc0, 0, 0, 0);
                        acc1 = __builtin_amdgcn_mfma_f32_16x16x32_bf16(a_hi, bh1[ks], acc1, 0, 0, 0);
                        acc1 = __builtin_amdgcn_mfma_f32_16x16x32_bf16(a_lo, bh1[ks], acc1, 0, 0, 0);
                        acc1 = __builtin_amdgcn_mfma_f32_16x16x32_bf16(a_hi, bl1[ks], acc1, 0, 0, 0);
                    }
                    // scatter: C row = s*16 + quad*4 + reg, col = cb*16 + m
#pragma unroll
                    for (int reg = 0; reg < 4; ++reg) {
                        const int prow = s * 16 + quad * 4 + reg;
                        const int orow = omr[prow];          // 0 for padded rows (acc=0)
                        float* dst = accs + orow * 132 + m;
                        atomicAdd(dst + cb0 * 16, acc0[reg]);
                        atomicAdd(dst + (cb0 + 1) * 16, acc1[reg]);
                    }
                }
                __syncthreads();
            }
        }
        sk = ek;
    }

    // --- write tile once, coalesced float4 (accs row stride 33 float4) ---
    {
        const int c4 = t & 31;
        const int rg = t >> 5;
        float4* dst4 = (float4*)(out + (long)b * 64 * Cc);
        const float4* a4 = (const float4*)accs;
#pragma unroll
        for (int i = 0; i < 8; ++i) {
            const int r = rg * 8 + i;
            dst4[r * 32 + c4] = a4[r * 33 + c4];
        }
    }
    // --- fused per-channel partial stats ---
    {
        const int col  = t & 127;
        const int half = t >> 7;
        float s = 0.f, q = 0.f;
        for (int r = half * 32; r < half * 32 + 32; ++r) {
            float v = accs[r * 132 + col];
            s += v; q += v * v;
        }
        if (half) { sred[col] = s; qred[col] = q; }
        __syncthreads();
        if (!half) {
            s += sred[col]; q += qred[col];
            unsafeAtomicAdd(&stats[col], s);
            unsafeAtomicAdd(&stats[Cc + col], q);
        }
    }
}

// ---------------------------------------------------------------------------
// Kernel 7: finalize BN scale/shift per channel
// ---------------------------------------------------------------------------
__global__ void finalize_kernel(const float* __restrict__ gamma,
                                const float* __restrict__ beta,
                                float* __restrict__ stats) {
    int c = threadIdx.x;
    float inv_n = 1.0f / (float)NOUTc;
    float mean = stats[c] * inv_n;
    float var  = stats[Cc + c] * inv_n - mean * mean;
    float scale = gamma[c] * rsqrtf(var + EPSc);
    stats[2 * Cc + c] = scale;
    stats[3 * Cc + c] = beta[c] - mean * scale;
}

// ---------------------------------------------------------------------------
// Kernel 8: in-place normalize  y = out*scale[c] + shift[c]
// ---------------------------------------------------------------------------
__global__ __launch_bounds__(256) void norm_kernel(float4* __restrict__ out4,
                                                   const float* __restrict__ stats) {
    const float4* stats4 = (const float4*)stats;
    int idx0 = blockIdx.x * blockDim.x + threadIdx.x;
    int c4 = idx0 & 31;
    float4 sc = stats4[64 + c4];
    float4 sh = stats4[96 + c4];
    const int n4 = NOUTc * (Cc / 4);
    const int stride = gridDim.x * blockDim.x;
    for (int i = idx0; i < n4; i += stride) {
        float4 v = out4[i];
        v.x = v.x * sc.x + sh.x;
        v.y = v.y * sc.y + sh.y;
        v.z = v.z * sc.z + sh.z;
        v.w = v.w * sc.w + sh.w;
        out4[i] = v;
    }
}

// ---------------------------------------------------------------------------
extern "C" void kernel_launch(void* const* d_in, const int* in_sizes, int n_in,
                              void* d_out, int out_size, void* d_ws, size_t ws_size,
                              hipStream_t stream) {
    const float* feats    = (const float*)d_in[0];
    const float* W        = (const float*)d_in[1];
    const float* gamma    = (const float*)d_in[2];
    const float* beta     = (const float*)d_in[3];
    const int*   in_maps  = (const int*)d_in[4];
    const int*   out_maps = (const int*)d_in[5];
    float* out = (float*)d_out;

    char* ws = (char*)d_ws;
    float*    stats     = (float*)(ws + WS_STATS);
    unsigned* counts    = (unsigned*)(ws + WS_COUNTS);
    unsigned* aux       = (unsigned*)(ws + WS_AUX);
    unsigned* sorted_pk = (unsigned*)(ws + WS_SPK);
    short8*   wfh       = (short8*)(ws + WS_WFH);
    short8*   wfl       = (short8*)(ws + WS_WFL);

    zero2_kernel<<<660, 256, 0, stream>>>(stats, counts);
    wprep_kernel<<<216, 256, 0, stream>>>(W, wfh, wfl);
    hist2_kernel<<<K3c * BPK, 256, 0, stream>>>(out_maps, counts);
    scan_a<<<SCANB, 1024, 0, stream>>>(counts, aux);
    scan_b<<<1, 256, 0, stream>>>(aux);
    scan_c<<<SCANB, 1024, 0, stream>>>(counts, aux);
    build2_kernel<<<K3c * BPK, 256, 0, stream>>>(in_maps, out_maps, counts, sorted_pk);
    gemm3_kernel<<<NBUCK, 256, 0, stream>>>(feats, wfh, wfl, counts, sorted_pk, out, stats);
    finalize_kernel<<<1, 128, 0, stream>>>(gamma, beta, stats);
    norm_kernel<<<4096, 256, 0, stream>>>((float4*)out, stats);
}

// Round 3
// 2514.988 us; speedup vs baseline: 1.4174x; 1.4174x over previous
//
#include <hip/hip_runtime.h>
#include <hip/hip_fp16.h>

// Problem constants (fixed by reference)
#define K3c    27
#define Mc     100000
#define NINc   200000
#define NOUTc  400000
#define Cc     128
#define EPSc   1e-5f

#define NBUCK  6250            // 64-row output buckets (NOUTc/64)
#define NCNTA  (K3c * NBUCK)   // 168,750 per-(k,bucket) counters (A-sort)
#define NCNTG  NOUTc           // 400,000 per-om counters (G-sort)
#define BPK    391             // map-pass blocks per k (391*256 >= 100000)
#define SCANBA 165             // ceil(168750/1024)
#define SCANBG 391             // ceil(400000/1024)

// ws layout (byte offsets)
#define WS_STATS   0u          // 512 floats: sum | ssq | scale | shift
#define WS_CNTA    4096u       // NCNTA u32
#define WS_AUXA    679936u     // SCANBA u32
#define WS_CNTG    681984u     // NCNTG u32
#define WS_AUXG    2282496u    // SCANBG u32
#define WS_WFH     2285568u    // 27*2048 lanes * 8 shorts (884,736 B)
#define WS_WFL     3170304u    // same
#define WS_SIMA    4055040u    // 2.7M int: im in (k, om-bucket)-sorted order
#define WS_PGA     14855040u   // 2.7M u32: global om-sorted position per A-entry
#define WS_CBUF    25657344u   // contribution buffer (rest of ws)

typedef __attribute__((ext_vector_type(8))) short short8;
typedef __attribute__((ext_vector_type(4))) float f32x4;

__device__ inline unsigned fbits(float f) { return __builtin_bit_cast(unsigned, f); }
__device__ inline float bfloat(unsigned u) { return __builtin_bit_cast(float, u); }

__device__ inline unsigned pack_hi2(float f0, float f1) {
    return (fbits(f0) >> 16) | (fbits(f1) & 0xFFFF0000u);
}
__device__ inline float trunc_bf16_f(float f) { return bfloat(fbits(f) & 0xFFFF0000u); }

__device__ inline unsigned short bf16_rne(float f) {
    unsigned u = fbits(f);
    u += 0x7FFFu + ((u >> 16) & 1u);
    return (unsigned short)(u >> 16);
}

__device__ inline unsigned short f2h(float f) { return __half_as_ushort(__float2half(f)); }
__device__ inline float h2f(unsigned short u) { return __half2float(__ushort_as_half(u)); }

// store/load helpers for the templated contribution buffer
__device__ inline void storeC(unsigned short* p, float v) { *p = f2h(v); }
__device__ inline void storeC(float* p, float v) { *p = v; }

// ---------------------------------------------------------------------------
// Kernel 1: zero counters + stats (out needs no zeroing: phase B writes all)
// ---------------------------------------------------------------------------
__global__ __launch_bounds__(256) void zero3_kernel(float* __restrict__ stats,
                                                    unsigned* __restrict__ cntA,
                                                    unsigned* __restrict__ cntG) {
    int idx = blockIdx.x * 256 + threadIdx.x;
    if (idx < NCNTA) cntA[idx] = 0u;
    if (idx < NCNTG) cntG[idx] = 0u;
    if (idx < 512) stats[idx] = 0.f;
}

// ---------------------------------------------------------------------------
// Kernel 2: W -> per-lane MFMA B-fragment layout, RNE hi/lo bf16 split
// ---------------------------------------------------------------------------
__global__ __launch_bounds__(256) void wprep_kernel(const float* __restrict__ W,
                                                    short8* __restrict__ wfh,
                                                    short8* __restrict__ wfl) {
    int tid = blockIdx.x * 256 + threadIdx.x;     // grid = 216 blocks exactly
    int k     = tid >> 11;
    int rem   = tid & 2047;
    int kstep = rem >> 9;
    int cb    = (rem >> 6) & 7;
    int lane  = rem & 63;
    int n   = cb * 16 + (lane & 15);
    int kk0 = kstep * 32 + (lane >> 4) * 8;
    const float* src = W + k * (Cc * Cc) + kk0 * Cc + n;
    short8 h, l;
#pragma unroll
    for (int j = 0; j < 8; ++j) {
        float f = src[j * Cc];
        unsigned short hb = bf16_rne(f);
        h[j] = (short)hb;
        float hf = bfloat(((unsigned)hb) << 16);
        l[j] = (short)bf16_rne(f - hf);
    }
    wfh[tid] = h;
    wfl[tid] = l;
}

// ---------------------------------------------------------------------------
// Kernel 3: dual histogram — per-(k,bucket) (A order) and per-om (G order)
// ---------------------------------------------------------------------------
__global__ __launch_bounds__(256) void hist3_kernel(const int* __restrict__ out_maps,
                                                    unsigned* __restrict__ cntA,
                                                    unsigned* __restrict__ cntG) {
    int b = blockIdx.x;
    int k = b / BPK;
    int m = (b - k * BPK) * 256 + threadIdx.x;
    if (m < Mc) {
        int om = out_maps[k * Mc + m];
        atomicAdd(&cntA[k * NBUCK + (om >> 6)], 1u);
        atomicAdd(&cntG[om], 1u);
    }
}

// ---------------------------------------------------------------------------
// Kernels 4a/4b/4c: generic multi-block exclusive scan (n <= 1024*1024)
// ---------------------------------------------------------------------------
__global__ __launch_bounds__(1024) void scan_a(unsigned* __restrict__ c,
                                               unsigned* __restrict__ aux, int n) {
    __shared__ unsigned lds[1024];
    const int t = threadIdx.x;
    const int i = blockIdx.x * 1024 + t;
    unsigned v = (i < n) ? c[i] : 0u;
    lds[t] = v;
    __syncthreads();
    for (int off = 1; off < 1024; off <<= 1) {
        unsigned x = (t >= off) ? lds[t - off] : 0u;
        __syncthreads();
        lds[t] += x;
        __syncthreads();
    }
    if (i < n) c[i] = lds[t] - v;
    if (t == 1023) aux[blockIdx.x] = lds[1023];
}

__global__ __launch_bounds__(1024) void scan_b(unsigned* __restrict__ aux, int nb) {
    __shared__ unsigned lds[1024];
    const int t = threadIdx.x;
    unsigned v = (t < nb) ? aux[t] : 0u;
    lds[t] = v;
    __syncthreads();
    for (int off = 1; off < 1024; off <<= 1) {
        unsigned x = (t >= off) ? lds[t - off] : 0u;
        __syncthreads();
        lds[t] += x;
        __syncthreads();
    }
    if (t < nb) aux[t] = lds[t] - v;
}

__global__ __launch_bounds__(1024) void scan_c(unsigned* __restrict__ c,
                                               const unsigned* __restrict__ aux, int n) {
    const int i = blockIdx.x * 1024 + threadIdx.x;
    if (i < n) c[i] += aux[blockIdx.x];
}

// ---------------------------------------------------------------------------
// Kernel 5: build both sort structures in one pass.
//   posA: position in (k-major, om-bucket) order -> sorted_imA[posA] = im
//   posG: position in global om-sorted order     -> pgA[posA] = posG
// After this, cntA/cntG hold END offsets of each cell's range.
// ---------------------------------------------------------------------------
__global__ __launch_bounds__(256) void build3_kernel(const int* __restrict__ in_maps,
                                                     const int* __restrict__ out_maps,
                                                     unsigned* __restrict__ cntA,
                                                     unsigned* __restrict__ cntG,
                                                     int* __restrict__ simA,
                                                     unsigned* __restrict__ pgA) {
    int b = blockIdx.x;
    int k = b / BPK;
    int m = (b - k * BPK) * 256 + threadIdx.x;
    if (m < Mc) {
        int om = out_maps[k * Mc + m];
        int im = in_maps[k * Mc + m];
        unsigned posA = atomicAdd(&cntA[k * NBUCK + (om >> 6)], 1u);
        unsigned posG = atomicAdd(&cntG[om], 1u);
        simA[posA] = im;
        pgA[posA]  = posG;
    }
}

// ---------------------------------------------------------------------------
// Kernel 6 (phase A): dense k-major split-bf16 MFMA GEMM over 64-pair chunks,
// writing each pair's fp32/fp16 contribution row into cbuf at its om-sorted
// position (minus slab base). Structure identical to the proven 1316us kernel;
// only the epilogue (atomics -> stores) and row source (slab ranges) differ.
// Slab s covers om-buckets [B0,B1): per k, a contiguous range of its sorted
// pairs; per slab, a contiguous range of om-sorted positions.
// ---------------------------------------------------------------------------
template <typename ST>
__global__ __launch_bounds__(256) void phaseA_kernel(
    const float* __restrict__ feats,
    const short8* __restrict__ wfh, const short8* __restrict__ wfl,
    const unsigned* __restrict__ endA,   // cntA after build (end offsets)
    const unsigned* __restrict__ endG,   // cntG after build (end offsets)
    const int* __restrict__ simA, const unsigned* __restrict__ pgA,
    ST* __restrict__ cbuf, int B0, int B1, int CPSL, unsigned capRows)
{
    __shared__ short fsh[64 * 136];
    __shared__ short fsl[64 * 136];
    __shared__ unsigned posr[64];

    const int t  = threadIdx.x;
    const int bx = blockIdx.x;
    const int k  = bx / CPSL;
    const int ci = bx - k * CPSL;
    const unsigned lo = (k == 0 && B0 == 0) ? 0u : endA[k * NBUCK + B0 - 1];
    const unsigned hi = endA[k * NBUCK + B1 - 1];
    const unsigned start = lo + (unsigned)ci * 64u;
    if (start >= hi) return;
    const int valid = (int)(hi - start < 64u ? hi - start : 64u);
    const unsigned slabBase = (B0 == 0) ? 0u : endG[B0 * 64 - 1];

    // --- gather 64 feats rows, trunc-split fp32 -> bf16 hi/lo into LDS ---
    {
        const int r  = t >> 2;
        const int cg = t & 3;
        const bool ok = (r < valid);
        long im = ok ? (long)simA[start + r] : 0;
        if (cg == 0) posr[r] = ok ? (pgA[start + r] - slabBase) : 0xFFFFFFFFu;
        const float4* src4 = (const float4*)(feats + im * Cc + cg * 32);
        unsigned* fh32 = (unsigned*)fsh;
        unsigned* fl32 = (unsigned*)fsl;
#pragma unroll
        for (int j = 0; j < 8; ++j) {
            float4 v = ok ? src4[j] : make_float4(0.f, 0.f, 0.f, 0.f);
            int col = cg * 32 + j * 4;
            int idx = r * 68 + (col >> 1);
            fh32[idx]     = pack_hi2(v.x, v.y);
            fh32[idx + 1] = pack_hi2(v.z, v.w);
            float lx = v.x - trunc_bf16_f(v.x);
            float ly = v.y - trunc_bf16_f(v.y);
            float lz = v.z - trunc_bf16_f(v.z);
            float lw = v.w - trunc_bf16_f(v.w);
            fl32[idx]     = pack_hi2(lx, ly);
            fl32[idx + 1] = pack_hi2(lz, lw);
        }
    }
    __syncthreads();

    const int wave = t >> 6;
    const int lane = t & 63;
    const int m    = lane & 15;
    const int quad = lane >> 4;

    f32x4 acc[8];
#pragma unroll
    for (int cb = 0; cb < 8; ++cb) acc[cb] = (f32x4){0.f, 0.f, 0.f, 0.f};

    const int arow = wave * 16 + m;
    for (int kstep = 0; kstep < 4; ++kstep) {
        const short* ah = fsh + arow * 136 + kstep * 32 + quad * 8;
        const short* al = fsl + arow * 136 + kstep * 32 + quad * 8;
        short8 a_hi = *(const short8*)ah;
        short8 a_lo = *(const short8*)al;
        int fb = ((k * 4 + kstep) * 8) * 64 + lane;
#pragma unroll
        for (int cb = 0; cb < 8; ++cb) {
            short8 b_hi = wfh[fb + cb * 64];
            short8 b_lo = wfl[fb + cb * 64];
            acc[cb] = __builtin_amdgcn_mfma_f32_16x16x32_bf16(a_hi, b_hi, acc[cb], 0, 0, 0);
            acc[cb] = __builtin_amdgcn_mfma_f32_16x16x32_bf16(a_lo, b_hi, acc[cb], 0, 0, 0);
            acc[cb] = __builtin_amdgcn_mfma_f32_16x16x32_bf16(a_hi, b_lo, acc[cb], 0, 0, 0);
        }
    }

    // --- epilogue: plain stores to om-sorted slab positions ---
    // C/D layout: col = cb*16 + m, row = wave*16 + quad*4 + reg
    const int rbase = wave * 16 + quad * 4;
#pragma unroll
    for (int reg = 0; reg < 4; ++reg) {
        int row = rbase + reg;
        if (row < valid) {
            unsigned rp = posr[row];
            if (rp < capRows) {
                ST* dst = cbuf + (size_t)rp * Cc + m;
#pragma unroll
                for (int cb = 0; cb < 8; ++cb)
                    storeC(dst + cb * 16, acc[cb][reg]);
            }
        }
    }
}

// ---------------------------------------------------------------------------
// Kernel 7 (phase B): per-om segmented sum over contiguous contribution runs.
// Block = one 64-row bucket; thread (r = t>>2, cg = t&3) accumulates 32 cols
// of row r in registers, writes out exactly once. No atomics.
// ---------------------------------------------------------------------------
template <typename ST>
__global__ __launch_bounds__(256) void phaseB_kernel(
    const ST* __restrict__ cbuf, const unsigned* __restrict__ endG,
    float* __restrict__ out, int B0)
{
    __shared__ unsigned ends[66];
    const int t = threadIdx.x;
    const int bucket = B0 + blockIdx.x;
    const int om0 = bucket * 64;
    if (t < 65) ends[t] = (om0 + t == 0) ? 0u : endG[om0 + t - 1];
    if (t == 65) ends[65] = (B0 == 0) ? 0u : endG[B0 * 64 - 1];
    __syncthreads();
    const unsigned sbase = ends[65];
    const int r  = t >> 2;
    const int cg = t & 3;
    unsigned e0 = ends[r] - sbase;
    unsigned e1 = ends[r + 1] - sbase;

    float a[32];
#pragma unroll
    for (int j = 0; j < 32; ++j) a[j] = 0.f;

    for (unsigned e = e0; e < e1; ++e) {
        const ST* src = cbuf + (size_t)e * Cc + cg * 32;
        if constexpr (sizeof(ST) == 2) {
            const short8* s8 = (const short8*)src;
#pragma unroll
            for (int p = 0; p < 4; ++p) {
                short8 v = s8[p];
#pragma unroll
                for (int j = 0; j < 8; ++j)
                    a[p * 8 + j] += h2f((unsigned short)v[j]);
            }
        } else {
            const float4* f4 = (const float4*)src;
#pragma unroll
            for (int p = 0; p < 8; ++p) {
                float4 v = f4[p];
                a[p * 4 + 0] += v.x; a[p * 4 + 1] += v.y;
                a[p * 4 + 2] += v.z; a[p * 4 + 3] += v.w;
            }
        }
    }

    float4* dst = (float4*)(out + (size_t)(om0 + r) * Cc + cg * 32);
#pragma unroll
    for (int p = 0; p < 8; ++p)
        dst[p] = make_float4(a[p * 4], a[p * 4 + 1], a[p * 4 + 2], a[p * 4 + 3]);
}

// ---------------------------------------------------------------------------
// Kernel 8: per-channel sum and sum-of-squares over 400000 rows
// ---------------------------------------------------------------------------
__global__ __launch_bounds__(256) void stats_kernel(const float4* __restrict__ out4,
                                                    float* __restrict__ stats) {
    const int t  = threadIdx.x;
    const int tx = t & 31;
    const int ty = t >> 5;

    float4 s = make_float4(0.f, 0.f, 0.f, 0.f);
    float4 q = make_float4(0.f, 0.f, 0.f, 0.f);
    int row0 = blockIdx.x * 400 + ty;
    for (int j = 0; j < 50; ++j) {
        float4 v = out4[(row0 + j * 8) * 32 + tx];
        s.x += v.x; s.y += v.y; s.z += v.z; s.w += v.w;
        q.x += v.x * v.x; q.y += v.y * v.y; q.z += v.z * v.z; q.w += v.w * v.w;
    }

    __shared__ float4 redS[256];
    __shared__ float4 redQ[256];
    redS[t] = s; redQ[t] = q;
    __syncthreads();
    if (ty == 0) {
#pragma unroll
        for (int jj = 1; jj < 8; ++jj) {
            float4 o = redS[jj * 32 + tx];
            s.x += o.x; s.y += o.y; s.z += o.z; s.w += o.w;
            float4 oq = redQ[jj * 32 + tx];
            q.x += oq.x; q.y += oq.y; q.z += oq.z; q.w += oq.w;
        }
        unsafeAtomicAdd(&stats[tx * 4 + 0], s.x);
        unsafeAtomicAdd(&stats[tx * 4 + 1], s.y);
        unsafeAtomicAdd(&stats[tx * 4 + 2], s.z);
        unsafeAtomicAdd(&stats[tx * 4 + 3], s.w);
        unsafeAtomicAdd(&stats[Cc + tx * 4 + 0], q.x);
        unsafeAtomicAdd(&stats[Cc + tx * 4 + 1], q.y);
        unsafeAtomicAdd(&stats[Cc + tx * 4 + 2], q.z);
        unsafeAtomicAdd(&stats[Cc + tx * 4 + 3], q.w);
    }
}

// ---------------------------------------------------------------------------
// Kernel 9: finalize BN scale/shift per channel
// ---------------------------------------------------------------------------
__global__ void finalize_kernel(const float* __restrict__ gamma,
                                const float* __restrict__ beta,
                                float* __restrict__ stats) {
    int c = threadIdx.x;
    float inv_n = 1.0f / (float)NOUTc;
    float mean = stats[c] * inv_n;
    float var  = stats[Cc + c] * inv_n - mean * mean;
    float scale = gamma[c] * rsqrtf(var + EPSc);
    stats[2 * Cc + c] = scale;
    stats[3 * Cc + c] = beta[c] - mean * scale;
}

// ---------------------------------------------------------------------------
// Kernel 10: in-place normalize  y = out*scale[c] + shift[c]
// ---------------------------------------------------------------------------
__global__ __launch_bounds__(256) void norm_kernel(float4* __restrict__ out4,
                                                   const float* __restrict__ stats) {
    const float4* stats4 = (const float4*)stats;
    int idx0 = blockIdx.x * blockDim.x + threadIdx.x;
    int c4 = idx0 & 31;
    float4 sc = stats4[64 + c4];
    float4 sh = stats4[96 + c4];
    const int n4 = NOUTc * (Cc / 4);
    const int stride = gridDim.x * blockDim.x;
    for (int i = idx0; i < n4; i += stride) {
        float4 v = out4[i];
        v.x = v.x * sc.x + sh.x;
        v.y = v.y * sc.y + sh.y;
        v.z = v.z * sc.z + sh.z;
        v.w = v.w * sc.w + sh.w;
        out4[i] = v;
    }
}

// ---------------------------------------------------------------------------
extern "C" void kernel_launch(void* const* d_in, const int* in_sizes, int n_in,
                              void* d_out, int out_size, void* d_ws, size_t ws_size,
                              hipStream_t stream) {
    const float* feats    = (const float*)d_in[0];
    const float* W        = (const float*)d_in[1];
    const float* gamma    = (const float*)d_in[2];
    const float* beta     = (const float*)d_in[3];
    const int*   in_maps  = (const int*)d_in[4];
    const int*   out_maps = (const int*)d_in[5];
    float* out = (float*)d_out;

    char* ws = (char*)d_ws;
    float*    stats = (float*)(ws + WS_STATS);
    unsigned* cntA  = (unsigned*)(ws + WS_CNTA);
    unsigned* auxA  = (unsigned*)(ws + WS_AUXA);
    unsigned* cntG  = (unsigned*)(ws + WS_CNTG);
    unsigned* auxG  = (unsigned*)(ws + WS_AUXG);
    short8*   wfh   = (short8*)(ws + WS_WFH);
    short8*   wfl   = (short8*)(ws + WS_WFL);
    int*      simA  = (int*)(ws + WS_SIMA);
    unsigned* pgA   = (unsigned*)(ws + WS_PGA);

    zero3_kernel<<<1563, 256, 0, stream>>>(stats, cntA, cntG);
    wprep_kernel<<<216, 256, 0, stream>>>(W, wfh, wfl);
    hist3_kernel<<<K3c * BPK, 256, 0, stream>>>(out_maps, cntA, cntG);
    scan_a<<<SCANBA, 1024, 0, stream>>>(cntA, auxA, NCNTA);
    scan_b<<<1, 1024, 0, stream>>>(auxA, SCANBA);
    scan_c<<<SCANBA, 1024, 0, stream>>>(cntA, auxA, NCNTA);
    scan_a<<<SCANBG, 1024, 0, stream>>>(cntG, auxG, NCNTG);
    scan_b<<<1, 1024, 0, stream>>>(auxG, SCANBG);
    scan_c<<<SCANBG, 1024, 0, stream>>>(cntG, auxG, NCNTG);
    build3_kernel<<<K3c * BPK, 256, 0, stream>>>(in_maps, out_maps, cntA, cntG,
                                                 simA, pgA);

    // --- slab selection from ws_size (host-static, graph-capture safe) ---
    size_t cap = (ws_size > WS_CBUF) ? (size_t)(ws_size - WS_CBUF) : 0;
    auto slabs_for = [&](size_t eb) -> int {
        for (int n = 1; n <= 64; ++n) {
            double rows = 2700000.0 / n * 1.04 + 4096.0;
            if ((size_t)rows * 128ull * eb <= cap) return n;
        }
        return -1;
    };
    int n32 = slabs_for(4);
    int n16 = slabs_for(2);
    bool use_f32 = (n32 > 0 && n32 <= 8);        // prefer exact fp32 intermediate
    int nslab = use_f32 ? n32 : (n16 > 0 ? n16 : 64);
    const int SB = (NBUCK + nslab - 1) / nslab;
    const int CPSL = (int)(16.0 * SB * 1.10 / 64.0) + 3;

    for (int s = 0; s < nslab; ++s) {
        int B0 = s * SB;
        int B1 = (B0 + SB < NBUCK) ? B0 + SB : NBUCK;
        if (B0 >= B1) break;
        if (use_f32) {
            unsigned capRows = (unsigned)(cap / (128ull * 4ull));
            float* cbuf = (float*)(ws + WS_CBUF);
            phaseA_kernel<float><<<K3c * CPSL, 256, 0, stream>>>(
                feats, wfh, wfl, cntA, cntG, simA, pgA, cbuf, B0, B1, CPSL, capRows);
            phaseB_kernel<float><<<B1 - B0, 256, 0, stream>>>(cbuf, cntG, out, B0);
        } else {
            unsigned capRows = (unsigned)(cap / (128ull * 2ull));
            unsigned short* cbuf = (unsigned short*)(ws + WS_CBUF);
            phaseA_kernel<unsigned short><<<K3c * CPSL, 256, 0, stream>>>(
                feats, wfh, wfl, cntA, cntG, simA, pgA, cbuf, B0, B1, CPSL, capRows);
            phaseB_kernel<unsigned short><<<B1 - B0, 256, 0, stream>>>(cbuf, cntG, out, B0);
        }
    }

    stats_kernel<<<1000, 256, 0, stream>>>((const float4*)out, stats);
    finalize_kernel<<<1, 128, 0, stream>>>(gamma, beta, stats);
    norm_kernel<<<4096, 256, 0, stream>>>((float4*)out, stats);
}

// Round 4
// 2014.130 us; speedup vs baseline: 1.7698x; 1.2487x over previous
//
#include <hip/hip_runtime.h>
#include <hip/hip_fp16.h>

// Problem constants (fixed by reference)
#define K3c    27
#define Mc     100000
#define NINc   200000
#define NOUTc  400000
#define Cc     128
#define EPSc   1e-5f

#define NBUCK  6250            // 64-row output buckets (NOUTc/64)
#define NCNTA  (K3c * NBUCK)   // 168,750 per-(k,bucket) counters (A-sort)
#define NCNTG  NOUTc           // 400,000 per-om counters (G-sort)
#define BPK    391             // map-pass blocks per k (391*256 >= 100000)
#define SCANBA 165             // ceil(168750/1024)
#define SCANBG 391             // ceil(400000/1024)
#define NCH    4               // chunks per phaseA block

// ws layout (byte offsets)
#define WS_STATS   0u          // 512 floats: sum | ssq | scale | shift
#define WS_CNTA    4096u       // NCNTA u32
#define WS_AUXA    679936u     // SCANBA u32
#define WS_CNTG    681984u     // NCNTG u32
#define WS_AUXG    2282496u    // SCANBG u32
#define WS_WFH     2285568u    // 27*2048 lanes * 8 shorts (884,736 B)
#define WS_WFL     3170304u    // same
#define WS_SIMA    4055040u    // 2.7M int: im in (k, om-bucket)-sorted order
#define WS_PGA     14855040u   // 2.7M u32: global om-sorted position per A-entry
#define WS_CBUF    25657344u   // contribution buffer (rest of ws)

typedef __attribute__((ext_vector_type(8))) short short8;
typedef __attribute__((ext_vector_type(4))) float f32x4;

__device__ inline unsigned fbits(float f) { return __builtin_bit_cast(unsigned, f); }
__device__ inline float bfloat(unsigned u) { return __builtin_bit_cast(float, u); }

__device__ inline unsigned pack_hi2(float f0, float f1) {
    return (fbits(f0) >> 16) | (fbits(f1) & 0xFFFF0000u);
}
__device__ inline float trunc_bf16_f(float f) { return bfloat(fbits(f) & 0xFFFF0000u); }

__device__ inline unsigned short bf16_rne(float f) {
    unsigned u = fbits(f);
    u += 0x7FFFu + ((u >> 16) & 1u);
    return (unsigned short)(u >> 16);
}

__device__ inline unsigned short f2h(float f) { return __half_as_ushort(__float2half(f)); }
__device__ inline float h2f(unsigned short u) { return __half2float(__ushort_as_half(u)); }

// store helpers for the templated contribution buffer
__device__ inline void storeC(unsigned short* p, float v) { *p = f2h(v); }
__device__ inline void storeC(float* p, float v) { *p = v; }

// ---------------------------------------------------------------------------
// Kernel 1: zero counters + stats (out needs no zeroing: phase B writes all)
// ---------------------------------------------------------------------------
__global__ __launch_bounds__(256) void zero3_kernel(float* __restrict__ stats,
                                                    unsigned* __restrict__ cntA,
                                                    unsigned* __restrict__ cntG) {
    int idx = blockIdx.x * 256 + threadIdx.x;
    if (idx < NCNTA) cntA[idx] = 0u;
    if (idx < NCNTG) cntG[idx] = 0u;
    if (idx < 512) stats[idx] = 0.f;
}

// ---------------------------------------------------------------------------
// Kernel 2: W -> per-lane MFMA B-fragment layout, RNE hi/lo bf16 split
// ---------------------------------------------------------------------------
__global__ __launch_bounds__(256) void wprep_kernel(const float* __restrict__ W,
                                                    short8* __restrict__ wfh,
                                                    short8* __restrict__ wfl) {
    int tid = blockIdx.x * 256 + threadIdx.x;     // grid = 216 blocks exactly
    int k     = tid >> 11;
    int rem   = tid & 2047;
    int kstep = rem >> 9;
    int cb    = (rem >> 6) & 7;
    int lane  = rem & 63;
    int n   = cb * 16 + (lane & 15);
    int kk0 = kstep * 32 + (lane >> 4) * 8;
    const float* src = W + k * (Cc * Cc) + kk0 * Cc + n;
    short8 h, l;
#pragma unroll
    for (int j = 0; j < 8; ++j) {
        float f = src[j * Cc];
        unsigned short hb = bf16_rne(f);
        h[j] = (short)hb;
        float hf = bfloat(((unsigned)hb) << 16);
        l[j] = (short)bf16_rne(f - hf);
    }
    wfh[tid] = h;
    wfl[tid] = l;
}

// ---------------------------------------------------------------------------
// Kernel 3: dual histogram — per-(k,bucket) (A order) and per-om (G order)
// ---------------------------------------------------------------------------
__global__ __launch_bounds__(256) void hist3_kernel(const int* __restrict__ out_maps,
                                                    unsigned* __restrict__ cntA,
                                                    unsigned* __restrict__ cntG) {
    int b = blockIdx.x;
    int k = b / BPK;
    int m = (b - k * BPK) * 256 + threadIdx.x;
    if (m < Mc) {
        int om = out_maps[k * Mc + m];
        atomicAdd(&cntA[k * NBUCK + (om >> 6)], 1u);
        atomicAdd(&cntG[om], 1u);
    }
}

// ---------------------------------------------------------------------------
// Kernels 4a/4b/4c: generic multi-block exclusive scan (n <= 1024*1024)
// ---------------------------------------------------------------------------
__global__ __launch_bounds__(1024) void scan_a(unsigned* __restrict__ c,
                                               unsigned* __restrict__ aux, int n) {
    __shared__ unsigned lds[1024];
    const int t = threadIdx.x;
    const int i = blockIdx.x * 1024 + t;
    unsigned v = (i < n) ? c[i] : 0u;
    lds[t] = v;
    __syncthreads();
    for (int off = 1; off < 1024; off <<= 1) {
        unsigned x = (t >= off) ? lds[t - off] : 0u;
        __syncthreads();
        lds[t] += x;
        __syncthreads();
    }
    if (i < n) c[i] = lds[t] - v;
    if (t == 1023) aux[blockIdx.x] = lds[1023];
}

__global__ __launch_bounds__(1024) void scan_b(unsigned* __restrict__ aux, int nb) {
    __shared__ unsigned lds[1024];
    const int t = threadIdx.x;
    unsigned v = (t < nb) ? aux[t] : 0u;
    lds[t] = v;
    __syncthreads();
    for (int off = 1; off < 1024; off <<= 1) {
        unsigned x = (t >= off) ? lds[t - off] : 0u;
        __syncthreads();
        lds[t] += x;
        __syncthreads();
    }
    if (t < nb) aux[t] = lds[t] - v;
}

__global__ __launch_bounds__(1024) void scan_c(unsigned* __restrict__ c,
                                               const unsigned* __restrict__ aux, int n) {
    const int i = blockIdx.x * 1024 + threadIdx.x;
    if (i < n) c[i] += aux[blockIdx.x];
}

// ---------------------------------------------------------------------------
// Kernel 5: build both sort structures in one pass.
//   posA: position in (k-major, om-bucket) order -> simA[posA] = im
//   posG: position in global om-sorted order     -> pgA[posA] = posG
// After this, cntA/cntG hold END offsets of each cell's range.
// ---------------------------------------------------------------------------
__global__ __launch_bounds__(256) void build3_kernel(const int* __restrict__ in_maps,
                                                     const int* __restrict__ out_maps,
                                                     unsigned* __restrict__ cntA,
                                                     unsigned* __restrict__ cntG,
                                                     int* __restrict__ simA,
                                                     unsigned* __restrict__ pgA) {
    int b = blockIdx.x;
    int k = b / BPK;
    int m = (b - k * BPK) * 256 + threadIdx.x;
    if (m < Mc) {
        int om = out_maps[k * Mc + m];
        int im = in_maps[k * Mc + m];
        unsigned posA = atomicAdd(&cntA[k * NBUCK + (om >> 6)], 1u);
        unsigned posG = atomicAdd(&cntG[om], 1u);
        simA[posA] = im;
        pgA[posA]  = posG;
    }
}

// ---------------------------------------------------------------------------
// Kernel 6 (phase A), v2: pipelined multi-chunk MFMA GEMM.
// Block = NCH consecutive 64-pair chunks of one k (dense, same B panel).
//  - pair metadata (im, global pos) staged to LDS once per block
//  - column-split waves: wave w owns cols [32w,32w+32); its 16 B-fragments
//    live in registers for the whole block (loaded once per block)
//  - T14 split: chunk c+1's feats rows load into regs right after chunk c's
//    LDS split, hiding L3 gather latency under chunk c's MFMA phase
//  - epilogue: plain 64B-coalesced stores to om-sorted slab positions
// ---------------------------------------------------------------------------
template <typename ST>
__global__ __launch_bounds__(256, 3) void phaseA_kernel(
    const float* __restrict__ feats,
    const short8* __restrict__ wfh, const short8* __restrict__ wfl,
    const unsigned* __restrict__ endA,   // cntA after build (end offsets)
    const unsigned* __restrict__ endG,   // cntG after build (end offsets)
    const int* __restrict__ simA, const unsigned* __restrict__ pgA,
    ST* __restrict__ cbuf, int B0, int B1, int BPSL, unsigned capRows)
{
    __shared__ short fsh[64 * 136];
    __shared__ short fsl[64 * 136];
    __shared__ int      ims[NCH * 64];
    __shared__ unsigned poss[NCH * 64];

    const int t  = threadIdx.x;
    const int bx = blockIdx.x;
    const int k  = bx / BPSL;
    const int bi = bx - k * BPSL;
    const unsigned lo = (k == 0 && B0 == 0) ? 0u : endA[k * NBUCK + B0 - 1];
    const unsigned hi = endA[k * NBUCK + B1 - 1];
    const unsigned start0 = lo + (unsigned)bi * (NCH * 64u);
    if (start0 >= hi) return;
    const unsigned avail = hi - start0;
    const int navail = (int)(avail < (unsigned)(NCH * 64) ? avail : (unsigned)(NCH * 64));
    const int nchunk = (navail + 63) >> 6;
    const unsigned slabBase = (B0 == 0) ? 0u : endG[B0 * 64 - 1];

    // --- stage pair metadata for all chunks (one element per thread) ---
    if (t < navail) {
        ims[t]  = simA[start0 + t];
        poss[t] = pgA[start0 + t] - slabBase;
    } else {
        ims[t]  = 0;
        poss[t] = 0xFFFFFFFFu;
    }

    const int wave = t >> 6;
    const int lane = t & 63;
    const int m    = lane & 15;
    const int quad = lane >> 4;
    const int r    = t >> 2;          // staging row 0..63
    const int cg   = t & 3;           // staging col-group

    // --- B fragments (this k, this wave's 2 col-blocks): regs, whole block ---
    short8 Bh[8], Bl[8];              // [ks*2 + cbi]
#pragma unroll
    for (int ks = 0; ks < 4; ++ks) {
        const int fb = ((k * 4 + ks) * 8) * 64 + lane;
#pragma unroll
        for (int cbi = 0; cbi < 2; ++cbi) {
            Bh[ks * 2 + cbi] = wfh[fb + (wave * 2 + cbi) * 64];
            Bl[ks * 2 + cbi] = wfl[fb + (wave * 2 + cbi) * 64];
        }
    }

    __syncthreads();                  // ims/poss visible

    // --- prefetch chunk 0 rows into registers ---
    float4 fr[8];
    {
        const float4* s4 = (const float4*)(feats + (long)ims[r] * Cc + cg * 32);
#pragma unroll
        for (int j = 0; j < 8; ++j) fr[j] = s4[j];
    }

    for (int c = 0; c < nchunk; ++c) {
        // --- split fr -> LDS (uint2 stores) ---
        {
            unsigned* fh32 = (unsigned*)fsh;
            unsigned* fl32 = (unsigned*)fsl;
#pragma unroll
            for (int j = 0; j < 8; ++j) {
                float4 v = fr[j];
                int idx = r * 68 + cg * 16 + j * 2;
                uint2 hh, ll;
                hh.x = pack_hi2(v.x, v.y);
                hh.y = pack_hi2(v.z, v.w);
                float lx = v.x - trunc_bf16_f(v.x);
                float ly = v.y - trunc_bf16_f(v.y);
                float lz = v.z - trunc_bf16_f(v.z);
                float lw = v.w - trunc_bf16_f(v.w);
                ll.x = pack_hi2(lx, ly);
                ll.y = pack_hi2(lz, lw);
                *(uint2*)(fh32 + idx) = hh;
                *(uint2*)(fl32 + idx) = ll;
            }
        }
        // --- prefetch next chunk into fr (completes under MFMA below) ---
        if (c + 1 < nchunk) {
            const float4* s4 =
                (const float4*)(feats + (long)ims[(c + 1) * 64 + r] * Cc + cg * 32);
#pragma unroll
            for (int j = 0; j < 8; ++j) fr[j] = s4[j];
        }
        __syncthreads();

        f32x4 acc[4][2];
#pragma unroll
        for (int sub = 0; sub < 4; ++sub) {
            acc[sub][0] = (f32x4){0.f, 0.f, 0.f, 0.f};
            acc[sub][1] = (f32x4){0.f, 0.f, 0.f, 0.f};
        }

#pragma unroll
        for (int sub = 0; sub < 4; ++sub) {
            const short* ah = fsh + (sub * 16 + m) * 136 + quad * 8;
            const short* al = fsl + (sub * 16 + m) * 136 + quad * 8;
#pragma unroll
            for (int ks = 0; ks < 4; ++ks) {
                short8 a_hi = *(const short8*)(ah + ks * 32);
                short8 a_lo = *(const short8*)(al + ks * 32);
#pragma unroll
                for (int cbi = 0; cbi < 2; ++cbi) {
                    acc[sub][cbi] = __builtin_amdgcn_mfma_f32_16x16x32_bf16(
                        a_hi, Bh[ks * 2 + cbi], acc[sub][cbi], 0, 0, 0);
                    acc[sub][cbi] = __builtin_amdgcn_mfma_f32_16x16x32_bf16(
                        a_lo, Bh[ks * 2 + cbi], acc[sub][cbi], 0, 0, 0);
                    acc[sub][cbi] = __builtin_amdgcn_mfma_f32_16x16x32_bf16(
                        a_hi, Bl[ks * 2 + cbi], acc[sub][cbi], 0, 0, 0);
                }
            }
        }

        // --- epilogue: row = sub*16 + quad*4 + reg, col = (wave*2+cbi)*16 + m ---
        const int cvalid = (navail - c * 64) < 64 ? (navail - c * 64) : 64;
#pragma unroll
        for (int sub = 0; sub < 4; ++sub) {
#pragma unroll
            for (int reg = 0; reg < 4; ++reg) {
                int row = sub * 16 + quad * 4 + reg;
                if (row < cvalid) {
                    unsigned rp = poss[c * 64 + row];
                    if (rp < capRows) {
                        ST* dst = cbuf + (size_t)rp * Cc + m;
                        storeC(dst + (wave * 2 + 0) * 16, acc[sub][0][reg]);
                        storeC(dst + (wave * 2 + 1) * 16, acc[sub][1][reg]);
                    }
                }
            }
        }
        __syncthreads();
    }
}

// ---------------------------------------------------------------------------
// Kernel 7 (phase B): per-om segmented sum over contiguous contribution runs.
// Block = one 64-row bucket; thread (r = t>>2, cg = t&3) accumulates 32 cols
// of row r in registers, writes out exactly once. No atomics.
// ---------------------------------------------------------------------------
template <typename ST>
__global__ __launch_bounds__(256) void phaseB_kernel(
    const ST* __restrict__ cbuf, const unsigned* __restrict__ endG,
    float* __restrict__ out, int B0)
{
    __shared__ unsigned ends[66];
    const int t = threadIdx.x;
    const int bucket = B0 + blockIdx.x;
    const int om0 = bucket * 64;
    if (t < 65) ends[t] = (om0 + t == 0) ? 0u : endG[om0 + t - 1];
    if (t == 65) ends[65] = (B0 == 0) ? 0u : endG[B0 * 64 - 1];
    __syncthreads();
    const unsigned sbase = ends[65];
    const int r  = t >> 2;
    const int cg = t & 3;
    unsigned e0 = ends[r] - sbase;
    unsigned e1 = ends[r + 1] - sbase;

    float a[32];
#pragma unroll
    for (int j = 0; j < 32; ++j) a[j] = 0.f;

    for (unsigned e = e0; e < e1; ++e) {
        const ST* src = cbuf + (size_t)e * Cc + cg * 32;
        if constexpr (sizeof(ST) == 2) {
            const short8* s8 = (const short8*)src;
#pragma unroll
            for (int p = 0; p < 4; ++p) {
                short8 v = s8[p];
#pragma unroll
                for (int j = 0; j < 8; ++j)
                    a[p * 8 + j] += h2f((unsigned short)v[j]);
            }
        } else {
            const float4* f4 = (const float4*)src;
#pragma unroll
            for (int p = 0; p < 8; ++p) {
                float4 v = f4[p];
                a[p * 4 + 0] += v.x; a[p * 4 + 1] += v.y;
                a[p * 4 + 2] += v.z; a[p * 4 + 3] += v.w;
            }
        }
    }

    float4* dst = (float4*)(out + (size_t)(om0 + r) * Cc + cg * 32);
#pragma unroll
    for (int p = 0; p < 8; ++p)
        dst[p] = make_float4(a[p * 4], a[p * 4 + 1], a[p * 4 + 2], a[p * 4 + 3]);
}

// ---------------------------------------------------------------------------
// Kernel 8: per-channel sum and sum-of-squares over 400000 rows
// ---------------------------------------------------------------------------
__global__ __launch_bounds__(256) void stats_kernel(const float4* __restrict__ out4,
                                                    float* __restrict__ stats) {
    const int t  = threadIdx.x;
    const int tx = t & 31;
    const int ty = t >> 5;

    float4 s = make_float4(0.f, 0.f, 0.f, 0.f);
    float4 q = make_float4(0.f, 0.f, 0.f, 0.f);
    int row0 = blockIdx.x * 400 + ty;
    for (int j = 0; j < 50; ++j) {
        float4 v = out4[(row0 + j * 8) * 32 + tx];
        s.x += v.x; s.y += v.y; s.z += v.z; s.w += v.w;
        q.x += v.x * v.x; q.y += v.y * v.y; q.z += v.z * v.z; q.w += v.w * v.w;
    }

    __shared__ float4 redS[256];
    __shared__ float4 redQ[256];
    redS[t] = s; redQ[t] = q;
    __syncthreads();
    if (ty == 0) {
#pragma unroll
        for (int jj = 1; jj < 8; ++jj) {
            float4 o = redS[jj * 32 + tx];
            s.x += o.x; s.y += o.y; s.z += o.z; s.w += o.w;
            float4 oq = redQ[jj * 32 + tx];
            q.x += oq.x; q.y += oq.y; q.z += oq.z; q.w += oq.w;
        }
        unsafeAtomicAdd(&stats[tx * 4 + 0], s.x);
        unsafeAtomicAdd(&stats[tx * 4 + 1], s.y);
        unsafeAtomicAdd(&stats[tx * 4 + 2], s.z);
        unsafeAtomicAdd(&stats[tx * 4 + 3], s.w);
        unsafeAtomicAdd(&stats[Cc + tx * 4 + 0], q.x);
        unsafeAtomicAdd(&stats[Cc + tx * 4 + 1], q.y);
        unsafeAtomicAdd(&stats[Cc + tx * 4 + 2], q.z);
        unsafeAtomicAdd(&stats[Cc + tx * 4 + 3], q.w);
    }
}

// ---------------------------------------------------------------------------
// Kernel 9: finalize BN scale/shift per channel
// ---------------------------------------------------------------------------
__global__ void finalize_kernel(const float* __restrict__ gamma,
                                const float* __restrict__ beta,
                                float* __restrict__ stats) {
    int c = threadIdx.x;
    float inv_n = 1.0f / (float)NOUTc;
    float mean = stats[c] * inv_n;
    float var  = stats[Cc + c] * inv_n - mean * mean;
    float scale = gamma[c] * rsqrtf(var + EPSc);
    stats[2 * Cc + c] = scale;
    stats[3 * Cc + c] = beta[c] - mean * scale;
}

// ---------------------------------------------------------------------------
// Kernel 10: in-place normalize  y = out*scale[c] + shift[c]
// ---------------------------------------------------------------------------
__global__ __launch_bounds__(256) void norm_kernel(float4* __restrict__ out4,
                                                   const float* __restrict__ stats) {
    const float4* stats4 = (const float4*)stats;
    int idx0 = blockIdx.x * blockDim.x + threadIdx.x;
    int c4 = idx0 & 31;
    float4 sc = stats4[64 + c4];
    float4 sh = stats4[96 + c4];
    const int n4 = NOUTc * (Cc / 4);
    const int stride = gridDim.x * blockDim.x;
    for (int i = idx0; i < n4; i += stride) {
        float4 v = out4[i];
        v.x = v.x * sc.x + sh.x;
        v.y = v.y * sc.y + sh.y;
        v.z = v.z * sc.z + sh.z;
        v.w = v.w * sc.w + sh.w;
        out4[i] = v;
    }
}

// ---------------------------------------------------------------------------
extern "C" void kernel_launch(void* const* d_in, const int* in_sizes, int n_in,
                              void* d_out, int out_size, void* d_ws, size_t ws_size,
                              hipStream_t stream) {
    const float* feats    = (const float*)d_in[0];
    const float* W        = (const float*)d_in[1];
    const float* gamma    = (const float*)d_in[2];
    const float* beta     = (const float*)d_in[3];
    const int*   in_maps  = (const int*)d_in[4];
    const int*   out_maps = (const int*)d_in[5];
    float* out = (float*)d_out;

    char* ws = (char*)d_ws;
    float*    stats = (float*)(ws + WS_STATS);
    unsigned* cntA  = (unsigned*)(ws + WS_CNTA);
    unsigned* auxA  = (unsigned*)(ws + WS_AUXA);
    unsigned* cntG  = (unsigned*)(ws + WS_CNTG);
    unsigned* auxG  = (unsigned*)(ws + WS_AUXG);
    short8*   wfh   = (short8*)(ws + WS_WFH);
    short8*   wfl   = (short8*)(ws + WS_WFL);
    int*      simA  = (int*)(ws + WS_SIMA);
    unsigned* pgA   = (unsigned*)(ws + WS_PGA);

    zero3_kernel<<<1563, 256, 0, stream>>>(stats, cntA, cntG);
    wprep_kernel<<<216, 256, 0, stream>>>(W, wfh, wfl);
    hist3_kernel<<<K3c * BPK, 256, 0, stream>>>(out_maps, cntA, cntG);
    scan_a<<<SCANBA, 1024, 0, stream>>>(cntA, auxA, NCNTA);
    scan_b<<<1, 1024, 0, stream>>>(auxA, SCANBA);
    scan_c<<<SCANBA, 1024, 0, stream>>>(cntA, auxA, NCNTA);
    scan_a<<<SCANBG, 1024, 0, stream>>>(cntG, auxG, NCNTG);
    scan_b<<<1, 1024, 0, stream>>>(auxG, SCANBG);
    scan_c<<<SCANBG, 1024, 0, stream>>>(cntG, auxG, NCNTG);
    build3_kernel<<<K3c * BPK, 256, 0, stream>>>(in_maps, out_maps, cntA, cntG,
                                                 simA, pgA);

    // --- slab selection from ws_size (host-static, graph-capture safe) ---
    size_t cap = (ws_size > WS_CBUF) ? (size_t)(ws_size - WS_CBUF) : 0;
    auto slabs_for = [&](size_t eb) -> int {
        for (int n = 1; n <= 64; ++n) {
            double rows = 2700000.0 / n * 1.04 + 4096.0;
            if ((size_t)rows * 128ull * eb <= cap) return n;
        }
        return -1;
    };
    int n32 = slabs_for(4);
    int n16 = slabs_for(2);
    bool use_f32 = (n32 > 0 && n32 <= 8);        // prefer exact fp32 intermediate
    int nslab = use_f32 ? n32 : (n16 > 0 ? n16 : 64);
    const int SB = (NBUCK + nslab - 1) / nslab;
    const int CPSL = (int)(16.0 * SB * 1.10 / 64.0) + 3;   // 64-chunks per (k,slab)
    const int BPSL = (CPSL + NCH - 1) / NCH;               // blocks per (k,slab)

    for (int s = 0; s < nslab; ++s) {
        int B0 = s * SB;
        int B1 = (B0 + SB < NBUCK) ? B0 + SB : NBUCK;
        if (B0 >= B1) break;
        if (use_f32) {
            unsigned capRows = (unsigned)(cap / (128ull * 4ull));
            float* cbuf = (float*)(ws + WS_CBUF);
            phaseA_kernel<float><<<K3c * BPSL, 256, 0, stream>>>(
                feats, wfh, wfl, cntA, cntG, simA, pgA, cbuf, B0, B1, BPSL, capRows);
            phaseB_kernel<float><<<B1 - B0, 256, 0, stream>>>(cbuf, cntG, out, B0);
        } else {
            unsigned capRows = (unsigned)(cap / (128ull * 2ull));
            unsigned short* cbuf = (unsigned short*)(ws + WS_CBUF);
            phaseA_kernel<unsigned short><<<K3c * BPSL, 256, 0, stream>>>(
                feats, wfh, wfl, cntA, cntG, simA, pgA, cbuf, B0, B1, BPSL, capRows);
            phaseB_kernel<unsigned short><<<B1 - B0, 256, 0, stream>>>(cbuf, cntG, out, B0);
        }
    }

    stats_kernel<<<1000, 256, 0, stream>>>((const float4*)out, stats);
    finalize_kernel<<<1, 128, 0, stream>>>(gamma, beta, stats);
    norm_kernel<<<4096, 256, 0, stream>>>((float4*)out, stats);
}